// Round 1
// baseline (41.927 us; speedup 1.0000x reference)
//
#include <hip/hip_runtime.h>

#define B_SZ 4096
#define IN_D 256
#define OUT_D 256
#define NC 8
#define KTOT (IN_D * NC)   // 2048

#define BM 32
#define BN 128
#define KS 2
#define NSTEP 32           // (KTOT/KS)/32 K-steps of BK=32 (4 input features each)

using f32x4 = __attribute__((ext_vector_type(4))) float;
using s16x8 = __attribute__((ext_vector_type(8))) short;

__device__ __forceinline__ unsigned short f2bf(float f) {
    union { float f; unsigned int u; } v; v.f = f;
    unsigned int u = v.u;
    unsigned int r = (u + 0x7fffu + ((u >> 16) & 1u)) >> 16;  // RNE
    return (unsigned short)r;
}

__device__ __forceinline__ float fast_tanh(float x) {
    float e = __expf(2.0f * x);           // v_exp_f32-based; inf/0 saturate correctly
    return 1.0f - 2.0f / (e + 1.0f);
}

// ---------------------------------------------------------------------------
// Prep: W[i*8+j][o] = (1/IN) * ( spline_scale[i,o] * sum_c mono[c][j]*coefs[i,o,c]
//                                + (j==1 ? resid_scale[i] : 0) )
// stored bf16 in blocked layout Wg[(i*OUT + o)*8 + j]  == [K/8][N][8]
// ---------------------------------------------------------------------------
__global__ __launch_bounds__(256) void prep_w(
    const float* __restrict__ coefs, const float* __restrict__ alpha_at,
    const float* __restrict__ resid_scale, const float* __restrict__ spline_scale,
    unsigned short* __restrict__ Wg)
{
    __shared__ float mono[NC][NC];
    const int i = blockIdx.x;
    const int o = threadIdx.x;

    if (o == 0) {
        float al = tanhf(alpha_at[0]);
        float m[NC][NC];
        for (int a = 0; a < NC; a++)
            for (int b = 0; b < NC; b++) m[a][b] = 0.f;
        m[0][0] = 1.f;
        m[1][1] = al + 1.f;
        for (int n = 2; n < NC; n++) {
            float fn = (float)n;
            float c  = 2.f * fn + 2.f * al;
            float An = 2.f * fn * (fn + 2.f * al) * (c - 2.f);
            float Bn = (c - 1.f) * c * (c - 2.f);
            float Cn = 2.f * (fn + al - 1.f) * (fn + al - 1.f) * c;
            for (int j = 0; j < NC; j++) {
                float tm = (j > 0 ? m[n - 1][j - 1] : 0.f);
                m[n][j] = (Bn * tm - Cn * m[n - 2][j]) / An;
            }
        }
        for (int a = 0; a < NC; a++)
            for (int b = 0; b < NC; b++) mono[a][b] = m[a][b];
    }
    __syncthreads();

    float cf[NC];
    const float* cp = coefs + ((size_t)i * OUT_D + o) * NC;
    #pragma unroll
    for (int c = 0; c < NC; c++) cf[c] = cp[c];
    float ss = spline_scale[i * OUT_D + o];
    float rs = resid_scale[i];

    unsigned short w8[NC];
    #pragma unroll
    for (int j = 0; j < NC; j++) {
        float w = 0.f;
        #pragma unroll
        for (int c = 0; c < NC; c++) w += mono[c][j] * cf[c];
        w *= ss * (1.0f / IN_D);
        if (j == 1) w += rs * (1.0f / IN_D);
        w8[j] = f2bf(w);
    }
    uint4 pk;
    unsigned int* pu = (unsigned int*)&pk;
    #pragma unroll
    for (int h = 0; h < 4; h++)
        pu[h] = (unsigned int)w8[2 * h] | ((unsigned int)w8[2 * h + 1] << 16);
    *(uint4*)(Wg + ((size_t)i * OUT_D + o) * NC) = pk;
}

// ---------------------------------------------------------------------------
// GEMM: out[b,o] += sum_k A[b,k] * W[k,o], A[b, i*8+j] = tanh(x[b,i])^j (bf16)
// Block: BM=32 x BN=128, split-K=2, 256 threads (4 waves), double-buffered LDS.
// ---------------------------------------------------------------------------
__global__ __launch_bounds__(256) void kan_gemm(
    const float* __restrict__ x, const unsigned short* __restrict__ Wg,
    float* __restrict__ out)
{
    __shared__ __align__(16) unsigned short Wt[2][4 * BN * 8];  // 2 x 8 KB, [kg][n][j]
    __shared__ __align__(16) unsigned short At[2][4 * BM * 8];  // 2 x 2 KB, [kg][m][j]

    const int tid  = threadIdx.x;
    const int lane = tid & 63;
    const int w    = tid >> 6;
    const int bid  = blockIdx.x;
    const int ks   = bid & 1;
    const int nblk = (bid >> 1) & 1;
    const int mblk = bid >> 2;
    const int bm = mblk * BM, bn = nblk * BN;
    const int ibase0 = ks * (IN_D / KS);

    f32x4 acc[2][2];
    #pragma unroll
    for (int f = 0; f < 2; f++)
        #pragma unroll
        for (int g = 0; g < 2; g++)
            acc[f][g] = (f32x4){0.f, 0.f, 0.f, 0.f};

    auto stage = [&](int buf, int s) {
        const int ibase = ibase0 + s * 4;
        // W tile: 8 KB, layout identical global<->LDS, coalesced 16B/lane
        #pragma unroll
        for (int h = 0; h < 2; h++) {
            int f  = h * 2048 + tid * 8;          // flat ushort index in tile
            int il = f >> 10;
            int n  = (f >> 3) & 127;
            const uint4* src = (const uint4*)(Wg + ((size_t)(ibase + il) * OUT_D + bn + n) * 8);
            *(uint4*)(&Wt[buf][f]) = *src;
        }
        // A tile: 128 (b,i) pairs -> tanh + powers t^0..t^7
        if (tid < 128) {
            int m  = tid & 31;
            int il = tid >> 5;
            float xv = x[(size_t)(bm + m) * IN_D + (ibase + il)];
            float t = fast_tanh(xv);
            unsigned short q[8];
            float p = 1.f;
            #pragma unroll
            for (int j = 0; j < 8; j++) { q[j] = f2bf(p); p *= t; }
            uint4 pk;
            unsigned int* pu = (unsigned int*)&pk;
            #pragma unroll
            for (int h2 = 0; h2 < 4; h2++)
                pu[h2] = (unsigned int)q[2 * h2] | ((unsigned int)q[2 * h2 + 1] << 16);
            *(uint4*)(&At[buf][(il * BM + m) * 8]) = pk;
        }
    };

    stage(0, 0);
    __syncthreads();

    const int kg = lane >> 4;
    const int lr = lane & 15;

    for (int s = 0; s < NSTEP; ++s) {
        const int cur = s & 1;
        if (s + 1 < NSTEP) stage(cur ^ 1, s + 1);

        s16x8 af[2], bfr[2];
        #pragma unroll
        for (int f = 0; f < 2; f++)
            af[f] = *(const s16x8*)(&At[cur][(kg * BM + f * 16 + lr) * 8]);
        #pragma unroll
        for (int g = 0; g < 2; g++)
            bfr[g] = *(const s16x8*)(&Wt[cur][(kg * BN + w * 32 + g * 16 + lr) * 8]);

        #pragma unroll
        for (int f = 0; f < 2; f++)
            #pragma unroll
            for (int g = 0; g < 2; g++)
                acc[f][g] = __builtin_amdgcn_mfma_f32_16x16x32_bf16(af[f], bfr[g], acc[f][g], 0, 0, 0);

        __syncthreads();
    }

    // Epilogue: C/D layout col=lane&15, row=(lane>>4)*4+j  [verified m89]
    #pragma unroll
    for (int f = 0; f < 2; f++)
        #pragma unroll
        for (int g = 0; g < 2; g++)
            #pragma unroll
            for (int j = 0; j < 4; j++) {
                int r = bm + f * 16 + (lane >> 4) * 4 + j;
                int c = bn + w * 32 + g * 16 + lr;
                atomicAdd(&out[(size_t)r * OUT_D + c], acc[f][g][j]);
            }
}

extern "C" void kernel_launch(void* const* d_in, const int* in_sizes, int n_in,
                              void* d_out, int out_size, void* d_ws, size_t ws_size,
                              hipStream_t stream) {
    const float* x     = (const float*)d_in[0];
    const float* coefs = (const float*)d_in[1];
    const float* alpha = (const float*)d_in[2];
    const float* rs    = (const float*)d_in[3];
    const float* ss    = (const float*)d_in[4];
    float* out = (float*)d_out;
    unsigned short* Wg = (unsigned short*)d_ws;  // 2048*256 bf16 = 1 MB

    hipMemsetAsync(d_out, 0, (size_t)out_size * sizeof(float), stream);
    prep_w<<<dim3(IN_D), dim3(OUT_D), 0, stream>>>(coefs, alpha, rs, ss, Wg);
    kan_gemm<<<dim3((B_SZ / BM) * (OUT_D / BN) * KS), dim3(256), 0, stream>>>(x, Wg, out);
}

// Round 2
// 35.430 us; speedup vs baseline: 1.1834x; 1.1834x over previous
//
#include <hip/hip_runtime.h>

#define B_SZ 4096
#define IN_D 256
#define OUT_D 256
#define NC 8
#define KTOT (IN_D * NC)   // 2048

#define BM 32
#define BN 64
#define BK 64              // 8 input features per K-step
#define NSTEP (KTOT / BK)  // 32

using f32x4 = __attribute__((ext_vector_type(4))) float;
using s16x8 = __attribute__((ext_vector_type(8))) short;

__device__ __forceinline__ unsigned short f2bf(float f) {
    union { float f; unsigned int u; } v; v.f = f;
    unsigned int u = v.u;
    return (unsigned short)((u + 0x7fffu + ((u >> 16) & 1u)) >> 16);  // RNE
}

__device__ __forceinline__ float fast_tanh(float x) {
    float e = __expf(2.0f * x);   // saturates correctly at +-inf
    return 1.0f - 2.0f / (e + 1.0f);
}

// ---------------------------------------------------------------------------
// tanh prepass: t[b,i] = tanh(x[b,i])  (f32, so per-power rounding == R1)
// ---------------------------------------------------------------------------
__global__ __launch_bounds__(256) void tanh_pre(
    const float* __restrict__ x, float* __restrict__ t)
{
    int idx = blockIdx.x * 256 + threadIdx.x;
    t[idx] = fast_tanh(x[idx]);
}

// ---------------------------------------------------------------------------
// Prep: W[i*8+j][o] = (1/IN)*( spline_scale[i,o]*sum_c mono[c][j]*coefs[i,o,c]
//                              + (j==1 ? resid_scale[i] : 0) )
// bf16 blocked layout Wg[(i*OUT + o)*8 + j]
// ---------------------------------------------------------------------------
__global__ __launch_bounds__(256) void prep_w(
    const float* __restrict__ coefs, const float* __restrict__ alpha_at,
    const float* __restrict__ resid_scale, const float* __restrict__ spline_scale,
    unsigned short* __restrict__ Wg)
{
    __shared__ float mono[NC][NC];
    const int i = blockIdx.x;
    const int o = threadIdx.x;

    if (o == 0) {
        float al = tanhf(alpha_at[0]);
        float m[NC][NC];
        for (int a = 0; a < NC; a++)
            for (int b = 0; b < NC; b++) m[a][b] = 0.f;
        m[0][0] = 1.f;
        m[1][1] = al + 1.f;
        for (int n = 2; n < NC; n++) {
            float fn = (float)n;
            float c  = 2.f * fn + 2.f * al;
            float An = 2.f * fn * (fn + 2.f * al) * (c - 2.f);
            float Bn = (c - 1.f) * c * (c - 2.f);
            float Cn = 2.f * (fn + al - 1.f) * (fn + al - 1.f) * c;
            for (int j = 0; j < NC; j++) {
                float tm = (j > 0 ? m[n - 1][j - 1] : 0.f);
                m[n][j] = (Bn * tm - Cn * m[n - 2][j]) / An;
            }
        }
        for (int a = 0; a < NC; a++)
            for (int b = 0; b < NC; b++) mono[a][b] = m[a][b];
    }
    __syncthreads();

    float cf[NC];
    const float* cp = coefs + ((size_t)i * OUT_D + o) * NC;
    #pragma unroll
    for (int c = 0; c < NC; c++) cf[c] = cp[c];
    float ss = spline_scale[i * OUT_D + o];
    float rs = resid_scale[i];

    unsigned short w8[NC];
    #pragma unroll
    for (int j = 0; j < NC; j++) {
        float w = 0.f;
        #pragma unroll
        for (int c = 0; c < NC; c++) w += mono[c][j] * cf[c];
        w *= ss * (1.0f / IN_D);
        if (j == 1) w += rs * (1.0f / IN_D);
        w8[j] = f2bf(w);
    }
    uint4 pk;
    unsigned int* pu = (unsigned int*)&pk;
    #pragma unroll
    for (int h = 0; h < 4; h++)
        pu[h] = (unsigned int)w8[2 * h] | ((unsigned int)w8[2 * h + 1] << 16);
    *(uint4*)(Wg + ((size_t)i * OUT_D + o) * NC) = pk;
}

// ---------------------------------------------------------------------------
// GEMM: out[b,o] = sum_k A[b,k] * W[k,o],  A[b, i*8+j] = t[b,i]^j (bf16)
// Full-K per block: exclusive 32x64 tile, plain stores, no memset/atomics.
// 512 blocks (2/CU), 256 threads (4 waves), double-buffered LDS, BK=64.
// ---------------------------------------------------------------------------
__global__ __launch_bounds__(256) void kan_gemm(
    const float* __restrict__ t, const unsigned short* __restrict__ Wg,
    float* __restrict__ out)
{
    // Wt: [il(8)][n(64)][j(8)]  8 KB/buf; At: [il(8)][m(32)][j(8)] 4 KB/buf
    __shared__ __align__(16) unsigned short Wt[2][8 * BN * 8];
    __shared__ __align__(16) unsigned short At[2][8 * BM * 8];

    const int tid  = threadIdx.x;
    const int lane = tid & 63;
    const int w    = tid >> 6;
    const int lr   = lane & 15;
    const int kg   = lane >> 4;

    // XCD-aware bijective swizzle (512 blocks, 512 % 8 == 0)
    const int bid = blockIdx.x;
    const int swz = (bid & 7) * 64 + (bid >> 3);
    const int mblk = swz >> 2, nblk = swz & 3;
    const int bm = mblk * BM, bn = nblk * BN;

    f32x4 acc[2];
    acc[0] = (f32x4){0.f, 0.f, 0.f, 0.f};
    acc[1] = (f32x4){0.f, 0.f, 0.f, 0.f};

    const int a_m = tid & 31;       // A-gen: this thread's row
    const int a_il = tid >> 5;      //        and feature-within-step
    const float* trow = t + (size_t)(bm + a_m) * IN_D + a_il;

    auto stage = [&](int buf, int s) {
        const int ibase = s * 8;
        // W tile: 512 x 16B chunks, 2 per thread, coalesced
        #pragma unroll
        for (int h = 0; h < 2; h++) {
            int c  = h * 256 + tid;
            int il = c >> 6, n = c & 63;
            *(uint4*)(&Wt[buf][c * 8]) =
                *(const uint4*)(Wg + ((size_t)(ibase + il) * OUT_D + bn + n) * 8);
        }
        // A tile: one (m, il) pair per thread; LDS chunk index == tid (linear)
        float tv = trow[ibase];
        unsigned short q[8];
        float p = 1.f;
        #pragma unroll
        for (int j = 0; j < 8; j++) { q[j] = f2bf(p); p *= tv; }
        uint4 pk;
        unsigned int* pu = (unsigned int*)&pk;
        #pragma unroll
        for (int h2 = 0; h2 < 4; h2++)
            pu[h2] = (unsigned int)q[2 * h2] | ((unsigned int)q[2 * h2 + 1] << 16);
        *(uint4*)(&At[buf][tid * 8]) = pk;
    };

    stage(0, 0);
    __syncthreads();

    for (int s = 0; s < NSTEP; ++s) {
        const int cur = s & 1;
        if (s + 1 < NSTEP) stage(cur ^ 1, s + 1);

        s16x8 af[2][2], bfr[2];
        #pragma unroll
        for (int ks = 0; ks < 2; ks++) {
            const int il = ks * 4 + kg;
            bfr[ks] = *(const s16x8*)(&Wt[cur][(il * BN + w * 16 + lr) * 8]);
            #pragma unroll
            for (int f = 0; f < 2; f++)
                af[f][ks] = *(const s16x8*)(&At[cur][(il * BM + f * 16 + lr) * 8]);
        }
        #pragma unroll
        for (int f = 0; f < 2; f++)
            #pragma unroll
            for (int ks = 0; ks < 2; ks++)
                acc[f] = __builtin_amdgcn_mfma_f32_16x16x32_bf16(af[f][ks], bfr[ks], acc[f], 0, 0, 0);

        __syncthreads();
    }

    // Epilogue: C/D layout col=lane&15, row=(lane>>4)*4+j; exclusive tile
    #pragma unroll
    for (int f = 0; f < 2; f++)
        #pragma unroll
        for (int j = 0; j < 4; j++) {
            int r = bm + f * 16 + kg * 4 + j;
            int c = bn + w * 16 + lr;
            out[(size_t)r * OUT_D + c] = acc[f][j];
        }
}

extern "C" void kernel_launch(void* const* d_in, const int* in_sizes, int n_in,
                              void* d_out, int out_size, void* d_ws, size_t ws_size,
                              hipStream_t stream) {
    const float* x     = (const float*)d_in[0];
    const float* coefs = (const float*)d_in[1];
    const float* alpha = (const float*)d_in[2];
    const float* rs    = (const float*)d_in[3];
    const float* ss    = (const float*)d_in[4];
    float* out = (float*)d_out;

    unsigned short* Wg = (unsigned short*)d_ws;              // 1 MB
    float* tf = (float*)((char*)d_ws + (1 << 20));           // 4 MB

    tanh_pre<<<dim3(B_SZ * IN_D / 256), dim3(256), 0, stream>>>(x, tf);
    prep_w<<<dim3(IN_D), dim3(OUT_D), 0, stream>>>(coefs, alpha, rs, ss, Wg);
    kan_gemm<<<dim3((B_SZ / BM) * (OUT_D / BN)), dim3(256), 0, stream>>>(tf, Wg, out);
}